// Round 5
// baseline (667.838 us; speedup 1.0000x reference)
//
#include <hip/hip_runtime.h>
#include <stdint.h>

#define NPIX 65536
#define IGN (-255)
#define CAP 256
#define SPLIT 8

typedef unsigned long long u64;
typedef int v4i __attribute__((ext_vector_type(4)));

// ---- ws layout (u32 indices) ----
#define WS_HIST   0        // [256*256]
#define WS_LIT    65536    // [256] float bits
#define WS_ROI    65792    // [256]
#define WS_DONE1  66048    // [256]
#define WS_DONE2  66304    // [256]
#define WS_CNT    66560    // [256*2]
#define WS_U32_END 67072
#define WS_CAND_BYTE 268288  // u64[256][2][CAP] -> 1 MiB

// ---------------- threefry2x32 (exact JAX partitionable implementation) ----------------
__device__ __forceinline__ uint32_t rotl32(uint32_t v, uint32_t r){ return (v<<r)|(v>>(32u-r)); }

__device__ __forceinline__ void tf2x32(uint32_t k0, uint32_t k1, uint32_t x0, uint32_t x1,
                                       uint32_t &o0, uint32_t &o1){
  uint32_t k2 = k0 ^ k1 ^ 0x1BD11BDAu;
  x0 += k0; x1 += k1;
#define TFR(r) { x0 += x1; x1 = rotl32(x1,(r)); x1 ^= x0; }
  TFR(13u) TFR(15u) TFR(26u) TFR(6u)   x0 += k1; x1 += k2 + 1u;
  TFR(17u) TFR(29u) TFR(16u) TFR(24u)  x0 += k2; x1 += k0 + 2u;
  TFR(13u) TFR(15u) TFR(26u) TFR(6u)   x0 += k0; x1 += k1 + 3u;
  TFR(17u) TFR(29u) TFR(16u) TFR(24u)  x0 += k1; x1 += k2 + 4u;
  TFR(13u) TFR(15u) TFR(26u) TFR(6u)   x0 += k2; x1 += k0 + 5u;
#undef TFR
  o0 = x0; o1 = x1;
}

// specialized: x0 = 0, x1 = pix, k2 precomputed; returns o0 ^ o1 (partitionable bits)
__device__ __forceinline__ uint32_t tf_bits(uint32_t k0, uint32_t k1, uint32_t k2, uint32_t pix){
  uint32_t x0 = k0, x1 = pix + k1;
#define TFR(r) { x0 += x1; x1 = rotl32(x1,(r)); x1 ^= x0; }
  TFR(13u) TFR(15u) TFR(26u) TFR(6u)   x0 += k1; x1 += k2 + 1u;
  TFR(17u) TFR(29u) TFR(16u) TFR(24u)  x0 += k2; x1 += k0 + 2u;
  TFR(13u) TFR(15u) TFR(26u) TFR(6u)   x0 += k0; x1 += k1 + 3u;
  TFR(17u) TFR(29u) TFR(16u) TFR(24u)  x0 += k1; x1 += k2 + 4u;
  TFR(13u) TFR(15u) TFR(26u) TFR(6u)   x0 += k2; x1 += k0 + 5u;
#undef TFR
  return x0 ^ x1;
}

// pack score+index so that u64 max == (higher score, then lower index)
__device__ __forceinline__ u64 packCand(uint32_t bits, uint32_t pix){
  float f = __uint_as_float((bits >> 9) | 0x3f800000u) - 1.0f;  // jax uniform [0,1)
  uint32_t u = __float_as_uint(f) ^ 0x80000000u;                // monotone map (f>=0)
  return ((u64)u << 32) | (u64)(0xFFFFFFFFu - pix);
}

// sorted-descending 10-element list, sentinel 0
__device__ __forceinline__ void t10_insert(u64* l, u64 c){
  if (c > l[9]) {
    l[9] = c;
#pragma unroll
    for (int i = 9; i > 0; --i){
      u64 a = l[i-1], b2 = l[i];
      if (b2 > a){ l[i-1] = b2; l[i] = a; }
    }
  }
}

// ================= K0: zero ws counters =================
__global__ void k0_init(uint32_t* __restrict__ ws){
  int i = blockIdx.x*1024 + threadIdx.x;
  if (i < WS_U32_END) ws[i] = 0u;
}

// ================= K1: fill IGN + histogram + thresholds (last block) =================
__global__ __launch_bounds__(256)
void k1_hist(const float* __restrict__ x, int* __restrict__ out, uint32_t* __restrict__ ws){
  const int img = blockIdx.x >> 3;
  const int chk = blockIdx.x & 7;
  const int tid = threadIdx.x;
  const float4* x4 = (const float4*)(x + (size_t)img * NPIX);
  v4i* o4 = (v4i*)(out + (size_t)img * NPIX);

  __shared__ uint32_t h4[1024];           // [bin*4 + sub] sub-histograms
  __shared__ float csum[256], cvsum[256];
  __shared__ u64 s_best;
  __shared__ int s_imin, s_old;

  h4[tid] = 0u; h4[tid+256] = 0u; h4[tid+512] = 0u; h4[tid+768] = 0u;
  __syncthreads();

  const int sub = tid & 3;
  const v4i f4 = {IGN, IGN, IGN, IGN};
#pragma unroll
  for (int j = 0; j < 8; ++j){
    int p4 = chk*2048 + j*256 + tid;
    float4 v = x4[p4];
    __builtin_nontemporal_store(f4, &o4[p4]);
    uint32_t q0 = (uint32_t)min(max((int)floorf(v.x*255.0f),0),255);
    uint32_t q1 = (uint32_t)min(max((int)floorf(v.y*255.0f),0),255);
    uint32_t q2 = (uint32_t)min(max((int)floorf(v.z*255.0f),0),255);
    uint32_t q3 = (uint32_t)min(max((int)floorf(v.w*255.0f),0),255);
    atomicAdd(&h4[q0*4+sub],1u); atomicAdd(&h4[q1*4+sub],1u);
    atomicAdd(&h4[q2*4+sub],1u); atomicAdd(&h4[q3*4+sub],1u);
  }
  __syncthreads();
  uint32_t hsum = h4[tid*4] + h4[tid*4+1] + h4[tid*4+2] + h4[tid*4+3];
  if (hsum) atomicAdd(&ws[WS_HIST + img*256 + tid], hsum);
  __threadfence();
  __syncthreads();
  if (tid == 0) s_old = (int)atomicAdd(&ws[WS_DONE1 + img], 1u);
  __syncthreads();
  if (s_old != SPLIT-1) return;

  // ---- last block of this image: thresholds ----
  __threadfence();
  uint32_t h = atomicAdd(&ws[WS_HIST + img*256 + tid], 0u);   // atomic load
  if (tid == 0){ s_imin = 255; s_best = 0ull; }
  __syncthreads();
  if (h) atomicMin(&s_imin, tid);
  __syncthreads();
  const float img_min = (float)s_imin;
  csum[tid]  = (float)h;
  cvsum[tid] = (float)h * ((float)tid - img_min);
  __syncthreads();
  for (int off = 1; off < 256; off <<= 1){
    float a = 0.f, c2 = 0.f;
    if (tid >= off){ a = csum[tid-off]; c2 = cvsum[tid-off]; }
    __syncthreads();
    if (tid >= off){ csum[tid] += a; cvsum[tid] += c2; }
    __syncthreads();
  }
  {
    float s_tot_o = cvsum[255] + img_min * csum[255];   // exact ints < 2^24
    if (tid < 255){
      float w0 = csum[tid], w1 = 65536.0f - w0;
      float cs = cvsum[tid] + img_min * csum[tid];
      float m0 = cs / fmaxf(w0, 1e-12f);
      float m1 = (s_tot_o - cs) / fmaxf(w1, 1e-12f);
      float d = m0 - m1;
      float vb = (w0*w1) * (d*d);
      u64 pk = ((u64)__float_as_uint(vb) << 32) | (u64)(255 - tid);
      atomicMax(&s_best, pk);
    }
  }
  __syncthreads();
  if (tid == 0){
    int bestIdx = 255 - (int)(s_best & 0xFFFFFFFFull);
    float otsu = fminf(fmaxf((float)bestIdx, 1.0f), 254.0f);
    float n_tot = csum[255], s_tot = cvsum[255];
    float t_curr = otsu - img_min, t_prev = t_curr + 10.0f;
    int it = 0;
    while (fabsf(t_curr - t_prev) > 0.5f && it < 64){
      int idx = min(max((int)floorf(t_curr + img_min), 0), 255);
      float n_back = csum[idx], s_back = cvsum[idx];
      float n_fore = n_tot - n_back, s_fore = s_tot - s_back;
      float mean_back = (n_back > 0.0f) ? (s_back / fmaxf(n_back, 1.0f)) : 0.0f;
      float mean_fore = s_fore / fmaxf(n_fore, 1.0f);
      float t_next = (mean_back - mean_fore) /
                     (logf(fmaxf(mean_back, 1e-12f)) - logf(fmaxf(mean_fore, 1e-12f)));
      if (mean_back < 1e-12f) t_next = mean_fore * 0.5f;
      t_prev = t_curr; t_curr = t_next; ++it;
    }
    float lit = t_curr + img_min;
    ws[WS_LIT + img] = __float_as_uint(lit);
    int qcut = (int)floorf(lit) + 1;            // roi: q > lit  <=>  q >= qcut (q integer)
    uint32_t nroi;
    if (qcut <= 0)        nroi = NPIX;
    else if (qcut > 255)  nroi = 0u;
    else                  nroi = NPIX - (uint32_t)csum[qcut-1];
    ws[WS_ROI + img] = nroi;
  }
}

// ================= K2: score + collect + finalize (last block) =================
__global__ __launch_bounds__(256)
void k2_score(const float* __restrict__ x, int* __restrict__ out,
              uint32_t* __restrict__ ws, u64* __restrict__ cand){
  const int img = blockIdx.x >> 3;
  const int chk = blockIdx.x & 7;
  const int tid = threadIdx.x;
  const float4* x4 = (const float4*)(x + (size_t)img * NPIX);

  __shared__ uint32_t s_kw[4];
  __shared__ int s_old;
  __shared__ u64 smem[640];
  __shared__ u64 s_top[2][10];
  __shared__ int s_fail[2], s_pr[2][10], s_pc[2][10], s_np[2];

  if (tid < 2){
    uint32_t o0, o1;
    tf2x32(0u, 1u, 0u, (uint32_t)(2*img + tid), o0, o1);
    s_kw[2*tid] = o0; s_kw[2*tid+1] = o1;
  }
  __syncthreads();
  const float lit = __uint_as_float(ws[WS_LIT + img]);    // cross-kernel: plain load ok
  const int qcut = (int)floorf(lit) + 1;
  const uint32_t fk0 = s_kw[0], fk1 = s_kw[1], bk0 = s_kw[2], bk1 = s_kw[3];
  const uint32_t fk2 = fk0 ^ fk1 ^ 0x1BD11BDAu;
  const uint32_t bk2 = bk0 ^ bk1 ^ 0x1BD11BDAu;
  u64* c0p = cand + ((size_t)img*2 + 0)*CAP;
  u64* c1p = cand + ((size_t)img*2 + 1)*CAP;

#pragma unroll
  for (int j = 0; j < 8; ++j){
    int p4 = chk*2048 + j*256 + tid;
    float4 v = x4[p4];
    uint32_t pix0 = (uint32_t)(p4*4);
    float vv[4] = {v.x, v.y, v.z, v.w};
#pragma unroll
    for (int s = 0; s < 4; ++s){
      int q = min(max((int)floorf(vv[s]*255.0f),0),255);
      bool r = (q >= qcut);
      uint32_t bits = tf_bits(r?fk0:bk0, r?fk1:bk1, r?fk2:bk2, pix0 + (uint32_t)s);
      // mantissa-aligned cut: top 1/256 of score space; no tie straddles it
      if (bits >= 0xFF000000u){
        int r2 = r ? 0 : 1;
        uint32_t idx = atomicAdd(&ws[WS_CNT + img*2 + r2], 1u);
        if (idx < CAP) atomicExch((r2 ? c1p : c0p) + idx, packCand(bits, pix0 + (uint32_t)s));
      }
    }
  }
  __threadfence();
  __syncthreads();
  if (tid == 0) s_old = (int)atomicAdd(&ws[WS_DONE2 + img], 1u);
  __syncthreads();
  if (s_old != SPLIT-1) return;

  // ---- last block of this image: finalize ----
  __threadfence();
  const uint32_t nroi = ws[WS_ROI + img];                  // cross-kernel: plain load ok
  int c0 = (int)atomicAdd(&ws[WS_CNT + img*2 + 0], 0u);
  int c1 = (int)atomicAdd(&ws[WS_CNT + img*2 + 1], 0u);
  if (tid == 0){
    s_fail[0] = (c0 > CAP) || (c0 < 10 && c0 != (int)nroi);
    s_fail[1] = (c1 > CAP) || (c1 < 10 && c1 != (int)(NPIX - nroi));
  }
  __syncthreads();

  for (int r2 = 0; r2 < 2; ++r2){
    int cc = (r2 ? c1 : c0);
    if (!s_fail[r2]){
      int n = min(cc, CAP);
      if (tid < n) smem[tid] = atomicAdd((r2 ? c1p : c0p) + tid, 0ull);  // atomic load
      __syncthreads();
      if (tid == 0){
        u64 t[10];
#pragma unroll
        for (int i = 0; i < 10; ++i) t[i] = 0ull;
        for (int i = 0; i < n; ++i) t10_insert(t, smem[i]);
#pragma unroll
        for (int i = 0; i < 10; ++i) s_top[r2][i] = t[i];
      }
      __syncthreads();
    } else {
      // fallback (statistically never runs): wave 0 rescans the whole image
      if (tid < 64){
        uint32_t kk0 = s_kw[2*r2], kk1 = s_kw[2*r2+1], kk2 = kk0 ^ kk1 ^ 0x1BD11BDAu;
        u64 t[10];
#pragma unroll
        for (int i = 0; i < 10; ++i) t[i] = 0ull;
        for (int k = 0; k < 1024; ++k){
          uint32_t pix = (uint32_t)(tid + 64*k);
          float v = x[(size_t)img*NPIX + pix];
          int q = min(max((int)floorf(v*255.0f),0),255);
          bool r = (q >= qcut);
          if (r == (r2 == 0)){
            t10_insert(t, packCand(tf_bits(kk0, kk1, kk2, pix), pix));
          }
        }
#pragma unroll
        for (int i = 0; i < 10; ++i) smem[tid*10 + i] = t[i];
      }
      __syncthreads();
      if (tid == 0){
        u64 t[10];
#pragma unroll
        for (int i = 0; i < 10; ++i) t[i] = 0ull;
        for (int i = 0; i < 640; ++i) t10_insert(t, smem[i]);
#pragma unroll
        for (int i = 0; i < 10; ++i) s_top[r2][i] = t[i];
      }
      __syncthreads();
    }
  }

  // extract points
  if (tid < 2){
    int np = 0;
    for (int i = 0; i < 10; ++i){
      u64 e = s_top[tid][i];
      if (e){
        uint32_t pix = 0xFFFFFFFFu - (uint32_t)(e & 0xFFFFFFFFull);
        s_pr[tid][np] = (int)(pix >> 8);
        s_pc[tid][np] = (int)(pix & 255u);
        ++np;
      }
    }
    s_np[tid] = np;
  }
  __syncthreads();

  // write dilated seed patches (<=180 px); duplicate writers compute identical values
  int* outb = out + (size_t)img * NPIX;
  const int nfg = s_np[0], nbg = s_np[1];
  const int npts = nfg + nbg;
  if (tid < npts*9){
    int k = tid / 9, d = tid - k*9;
    int pr = (k < nfg) ? s_pr[0][k] : s_pr[1][k - nfg];
    int pc = (k < nfg) ? s_pc[0][k] : s_pc[1][k - nfg];
    pr += d/3 - 1; pc += d%3 - 1;
    if (pr >= 0 && pr < 256 && pc >= 0 && pc < 256){
      bool fgd = false, bgd = false;
      for (int i = 0; i < nfg; ++i) fgd |= (abs(pr - s_pr[0][i]) <= 1) && (abs(pc - s_pc[0][i]) <= 1);
      for (int i = 0; i < nbg; ++i) bgd |= (abs(pr - s_pr[1][i]) <= 1) && (abs(pc - s_pc[1][i]) <= 1);
      int val = (fgd && bgd) ? IGN : (fgd ? 1 : 0);
      outb[pr*256 + pc] = val;
    }
  }
}

extern "C" void kernel_launch(void* const* d_in, const int* in_sizes, int n_in,
                              void* d_out, int out_size, void* d_ws, size_t ws_size,
                              hipStream_t stream) {
  const float* x = (const float*)d_in[0];
  int* out = (int*)d_out;
  uint32_t* ws = (uint32_t*)d_ws;
  u64* cand = (u64*)((char*)d_ws + WS_CAND_BYTE);
  int B = in_sizes[0] / NPIX;

  k0_init<<<(WS_U32_END + 1023)/1024, 1024, 0, stream>>>(ws);
  k1_hist<<<B*SPLIT, 256, 0, stream>>>(x, out, ws);
  k2_score<<<B*SPLIT, 256, 0, stream>>>(x, out, ws, cand);
}

// Round 6
// 200.701 us; speedup vs baseline: 3.3275x; 3.3275x over previous
//
#include <hip/hip_runtime.h>
#include <stdint.h>

#define NPIX 65536
#define IGN (-255)
#define CAPB 96

typedef unsigned long long u64;
typedef int v4i __attribute__((ext_vector_type(4)));

// ---------------- threefry2x32 (exact JAX partitionable implementation) ----------------
__device__ __forceinline__ uint32_t rotl32(uint32_t v, uint32_t r){ return (v<<r)|(v>>(32u-r)); }

__device__ __forceinline__ void tf2x32(uint32_t k0, uint32_t k1, uint32_t x0, uint32_t x1,
                                       uint32_t &o0, uint32_t &o1){
  uint32_t k2 = k0 ^ k1 ^ 0x1BD11BDAu;
  x0 += k0; x1 += k1;
#define TFR(r) { x0 += x1; x1 = rotl32(x1,(r)); x1 ^= x0; }
  TFR(13u) TFR(15u) TFR(26u) TFR(6u)   x0 += k1; x1 += k2 + 1u;
  TFR(17u) TFR(29u) TFR(16u) TFR(24u)  x0 += k2; x1 += k0 + 2u;
  TFR(13u) TFR(15u) TFR(26u) TFR(6u)   x0 += k0; x1 += k1 + 3u;
  TFR(17u) TFR(29u) TFR(16u) TFR(24u)  x0 += k1; x1 += k2 + 4u;
  TFR(13u) TFR(15u) TFR(26u) TFR(6u)   x0 += k2; x1 += k0 + 5u;
#undef TFR
  o0 = x0; o1 = x1;
}

// specialized: x0 = 0, x1 = pix, k2 precomputed; returns o0 ^ o1 (partitionable bits)
__device__ __forceinline__ uint32_t tf_bits(uint32_t k0, uint32_t k1, uint32_t k2, uint32_t pix){
  uint32_t x0 = k0, x1 = pix + k1;
#define TFR(r) { x0 += x1; x1 = rotl32(x1,(r)); x1 ^= x0; }
  TFR(13u) TFR(15u) TFR(26u) TFR(6u)   x0 += k1; x1 += k2 + 1u;
  TFR(17u) TFR(29u) TFR(16u) TFR(24u)  x0 += k2; x1 += k0 + 2u;
  TFR(13u) TFR(15u) TFR(26u) TFR(6u)   x0 += k0; x1 += k1 + 3u;
  TFR(17u) TFR(29u) TFR(16u) TFR(24u)  x0 += k1; x1 += k2 + 4u;
  TFR(13u) TFR(15u) TFR(26u) TFR(6u)   x0 += k2; x1 += k0 + 5u;
#undef TFR
  return x0 ^ x1;
}

// pack score+index so that u64 max == (higher score, then lower index)
__device__ __forceinline__ u64 packCand(uint32_t bits, uint32_t pix){
  float f = __uint_as_float((bits >> 9) | 0x3f800000u) - 1.0f;  // jax uniform [0,1)
  uint32_t u = __float_as_uint(f) ^ 0x80000000u;                // monotone map (f>=0)
  return ((u64)u << 32) | (u64)(0xFFFFFFFFu - pix);
}

// sorted-descending 10-element list, sentinel 0
__device__ __forceinline__ void t10_insert(u64* l, u64 c){
  if (c > l[9]) {
    l[9] = c;
#pragma unroll
    for (int i = 9; i > 0; --i){
      u64 a = l[i-1], b2 = l[i];
      if (b2 > a){ l[i-1] = b2; l[i] = a; }
    }
  }
}

// ================= K1: fill IGN + partial histograms + u8 cache =================
__global__ __launch_bounds__(256)
void k1_hist(const float* __restrict__ x, int* __restrict__ out,
             uint32_t* __restrict__ phist, uint32_t* __restrict__ u8c, int use_u8){
  const int img = blockIdx.x >> 3;
  const int chk = blockIdx.x & 7;
  const int tid = threadIdx.x;
  const float4* x4 = (const float4*)(x + (size_t)img * NPIX);
  v4i* o4 = (v4i*)(out + (size_t)img * NPIX);

  __shared__ uint32_t h4[1024];   // [bin*4 + sub]
  h4[tid] = 0u; h4[tid+256] = 0u; h4[tid+512] = 0u; h4[tid+768] = 0u;
  __syncthreads();

  const int sub = tid & 3;
  const v4i f4 = {IGN, IGN, IGN, IGN};
#pragma unroll
  for (int j = 0; j < 8; ++j){
    int p4 = chk*2048 + j*256 + tid;
    float4 v = x4[p4];
    __builtin_nontemporal_store(f4, &o4[p4]);
    uint32_t q0 = (uint32_t)min(max((int)floorf(v.x*255.0f),0),255);
    uint32_t q1 = (uint32_t)min(max((int)floorf(v.y*255.0f),0),255);
    uint32_t q2 = (uint32_t)min(max((int)floorf(v.z*255.0f),0),255);
    uint32_t q3 = (uint32_t)min(max((int)floorf(v.w*255.0f),0),255);
    if (use_u8) u8c[(size_t)img*16384 + p4] = q0 | (q1<<8) | (q2<<16) | (q3<<24);
    atomicAdd(&h4[q0*4+sub],1u); atomicAdd(&h4[q1*4+sub],1u);
    atomicAdd(&h4[q2*4+sub],1u); atomicAdd(&h4[q3*4+sub],1u);
  }
  __syncthreads();
  // plain store of this block's partial histogram (no global atomics, no pre-zero)
  phist[(size_t)(img*8+chk)*256 + tid] = h4[tid*4] + h4[tid*4+1] + h4[tid*4+2] + h4[tid*4+3];
}

// ================= K2: thresholds (redundant per block) + scoring =================
__global__ __launch_bounds__(256)
void k2_score(const float* __restrict__ x, const uint32_t* __restrict__ u8c,
              const uint32_t* __restrict__ phist, uint32_t* __restrict__ qcutp,
              uint32_t* __restrict__ nroip, uint32_t* __restrict__ bcnt,
              u64* __restrict__ cand, int use_u8){
  const int img = blockIdx.x >> 3;
  const int chk = blockIdx.x & 7;
  const int tid = threadIdx.x;

  __shared__ float csum[256], cvsum[256];
  __shared__ u64 s_best;
  __shared__ int s_imin, s_qcut;
  __shared__ uint32_t s_kw[4], s_cnt[2];
  __shared__ u64 s_cand[2][CAPB];

  if (tid < 2){
    uint32_t o0, o1;
    tf2x32(0u, 1u, 0u, (uint32_t)(2*img + tid), o0, o1);
    s_kw[2*tid] = o0; s_kw[2*tid+1] = o1;
  }
  if (tid == 0){ s_imin = 255; s_best = 0ull; s_cnt[0] = 0u; s_cnt[1] = 0u; }

  // sum the 8 partial histograms (cross-kernel: plain loads are safe)
  uint32_t h = 0;
#pragma unroll
  for (int k = 0; k < 8; ++k) h += phist[(size_t)(img*8+k)*256 + tid];
  __syncthreads();
  if (h) atomicMin(&s_imin, tid);
  __syncthreads();
  const float img_min = (float)s_imin;
  csum[tid]  = (float)h;
  cvsum[tid] = (float)h * ((float)tid - img_min);
  __syncthreads();
  // Hillis-Steele scan: all partial sums are exact ints < 2^24 -> bit-exact vs cumsum
  for (int off = 1; off < 256; off <<= 1){
    float a = 0.f, c2 = 0.f;
    if (tid >= off){ a = csum[tid-off]; c2 = cvsum[tid-off]; }
    __syncthreads();
    if (tid >= off){ csum[tid] += a; cvsum[tid] += c2; }
    __syncthreads();
  }
  // Otsu argmax (first max wins)
  {
    float s_tot_o = cvsum[255] + img_min * csum[255];
    if (tid < 255){
      float w0 = csum[tid], w1 = 65536.0f - w0;
      float cs = cvsum[tid] + img_min * csum[tid];
      float m0 = cs / fmaxf(w0, 1e-12f);
      float m1 = (s_tot_o - cs) / fmaxf(w1, 1e-12f);
      float d = m0 - m1;
      float vb = (w0*w1) * (d*d);
      u64 pk = ((u64)__float_as_uint(vb) << 32) | (u64)(255 - tid);
      atomicMax(&s_best, pk);
    }
  }
  __syncthreads();
  if (tid == 0){
    int bestIdx = 255 - (int)(s_best & 0xFFFFFFFFull);
    float otsu = fminf(fmaxf((float)bestIdx, 1.0f), 254.0f);
    float n_tot = csum[255], s_tot = cvsum[255];
    float t_curr = otsu - img_min, t_prev = t_curr + 10.0f;
    int it = 0;
    while (fabsf(t_curr - t_prev) > 0.5f && it < 64){
      int idx = min(max((int)floorf(t_curr + img_min), 0), 255);
      float n_back = csum[idx], s_back = cvsum[idx];
      float n_fore = n_tot - n_back, s_fore = s_tot - s_back;
      float mean_back = (n_back > 0.0f) ? (s_back / fmaxf(n_back, 1.0f)) : 0.0f;
      float mean_fore = s_fore / fmaxf(n_fore, 1.0f);
      float t_next = (mean_back - mean_fore) /
                     (logf(fmaxf(mean_back, 1e-12f)) - logf(fmaxf(mean_fore, 1e-12f)));
      if (mean_back < 1e-12f) t_next = mean_fore * 0.5f;
      t_prev = t_curr; t_curr = t_next; ++it;
    }
    float lit = t_curr + img_min;
    int qcut = (int)floorf(lit) + 1;     // roi: q > lit  <=>  q >= qcut (q integer)
    s_qcut = qcut;
    if (chk == 0){
      uint32_t nroi;
      if (qcut <= 0)        nroi = NPIX;
      else if (qcut > 255)  nroi = 0u;
      else                  nroi = NPIX - (uint32_t)csum[qcut-1];
      qcutp[img] = (uint32_t)qcut;
      nroip[img] = nroi;
    }
  }
  __syncthreads();

  // scoring over this chunk; candidates collected with LDS atomics only
  const int qcut = s_qcut;
  const uint32_t fk0 = s_kw[0], fk1 = s_kw[1], bk0 = s_kw[2], bk1 = s_kw[3];
  const uint32_t fk2 = fk0 ^ fk1 ^ 0x1BD11BDAu;
  const uint32_t bk2 = bk0 ^ bk1 ^ 0x1BD11BDAu;
#pragma unroll
  for (int j = 0; j < 8; ++j){
    int p4 = chk*2048 + j*256 + tid;
    uint32_t w;
    if (use_u8){
      w = u8c[(size_t)img*16384 + p4];
    } else {
      float4 v = ((const float4*)(x + (size_t)img*NPIX))[p4];
      uint32_t q0 = (uint32_t)min(max((int)floorf(v.x*255.0f),0),255);
      uint32_t q1 = (uint32_t)min(max((int)floorf(v.y*255.0f),0),255);
      uint32_t q2 = (uint32_t)min(max((int)floorf(v.z*255.0f),0),255);
      uint32_t q3 = (uint32_t)min(max((int)floorf(v.w*255.0f),0),255);
      w = q0 | (q1<<8) | (q2<<16) | (q3<<24);
    }
    uint32_t pix0 = (uint32_t)(p4*4);
#pragma unroll
    for (int s = 0; s < 4; ++s){
      int q = (int)((w >> (8*s)) & 255u);
      bool r = (q >= qcut);
      uint32_t bits = tf_bits(r?fk0:bk0, r?fk1:bk1, r?fk2:bk2, pix0 + (uint32_t)s);
      // mantissa-aligned cut (top 1/256 of score space; no tie straddles it)
      if (bits >= 0xFF000000u){
        int r2 = r ? 0 : 1;
        uint32_t idx = atomicAdd(&s_cnt[r2], 1u);
        if (idx < CAPB) s_cand[r2][idx] = packCand(bits, pix0 + (uint32_t)s);
      }
    }
  }
  __syncthreads();
  if (tid < 2) bcnt[(size_t)(img*8+chk)*2 + tid] = s_cnt[tid];   // raw (uncapped)
  {
    int s = tid >> 7, idx = tid & 127;
    int n = min((int)s_cnt[s], CAPB);
    if (idx < n) cand[((size_t)(img*8+chk)*2 + s)*CAPB + idx] = s_cand[s][idx];
  }
}

// ================= K3: gather candidates, top-10, write seeds =================
__global__ __launch_bounds__(256)
void k3_final(const float* __restrict__ x, int* __restrict__ out,
              const uint32_t* __restrict__ qcutp, const uint32_t* __restrict__ nroip,
              const uint32_t* __restrict__ bcnt, const u64* __restrict__ cand){
  const int img = blockIdx.x;
  const int tid = threadIdx.x;

  __shared__ u64 sbuf[2560];
  __shared__ u64 s_top[2][10];
  __shared__ int s_off[2][9], s_fail[2];
  __shared__ uint32_t s_kw[4];
  __shared__ int s_pr[2][10], s_pc[2][10], s_np[2];

  if (tid < 2){
    uint32_t o0, o1;
    tf2x32(0u, 1u, 0u, (uint32_t)(2*img + tid), o0, o1);
    s_kw[2*tid] = o0; s_kw[2*tid+1] = o1;
  }
  if (tid == 0){
    uint32_t nroi = nroip[img];
    for (int s = 0; s < 2; ++s){
      int off = 0, fail = 0;
      for (int k = 0; k < 8; ++k){
        uint32_t raw = bcnt[(size_t)(img*8+k)*2 + s];
        if (raw > (uint32_t)CAPB) fail = 1;
        int ck = (int)min(raw, (uint32_t)CAPB);
        s_off[s][k] = off; off += ck;
      }
      s_off[s][8] = off;
      int region = s ? (int)(NPIX - nroi) : (int)nroi;
      if (off < 10 && off != region) fail = 1;
      s_fail[s] = fail;
    }
  }
  __syncthreads();

  // compact candidates into LDS: threads [0,128) stream0, [128,256) stream1
  {
    int s = tid >> 7, idx = tid & 127;
#pragma unroll
    for (int k = 0; k < 8; ++k){
      int ck = s_off[s][k+1] - s_off[s][k];
      if (idx < ck) sbuf[s*1280 + s_off[s][k] + idx] = cand[((size_t)(img*8+k)*2 + s)*CAPB + idx];
    }
  }
  __syncthreads();
  if (tid == 0 || tid == 128){
    int s = tid >> 7;
    if (!s_fail[s]){
      u64 t[10];
#pragma unroll
      for (int i = 0; i < 10; ++i) t[i] = 0ull;
      int n = s_off[s][8];
      for (int i = 0; i < n; ++i) t10_insert(t, sbuf[s*1280 + i]);
#pragma unroll
      for (int i = 0; i < 10; ++i) s_top[s][i] = t[i];
    }
  }
  __syncthreads();

  // fallback rescan (statistically never runs; guarantees correctness)
  const int qcut = (int)qcutp[img];
  for (int s = 0; s < 2; ++s){
    if (!s_fail[s]) continue;          // uniform branch (shared)
    uint32_t kk0 = s_kw[2*s], kk1 = s_kw[2*s+1], kk2 = kk0 ^ kk1 ^ 0x1BD11BDAu;
    u64 t[10];
#pragma unroll
    for (int i = 0; i < 10; ++i) t[i] = 0ull;
    for (int k = 0; k < 256; ++k){
      uint32_t pix = (uint32_t)(tid + 256*k);
      float v = x[(size_t)img*NPIX + pix];
      int q = min(max((int)floorf(v*255.0f),0),255);
      bool r = (q >= qcut);
      if (r == (s == 0)) t10_insert(t, packCand(tf_bits(kk0, kk1, kk2, pix), pix));
    }
#pragma unroll
    for (int i = 0; i < 10; ++i) sbuf[tid*10 + i] = t[i];
    __syncthreads();
    if (tid == 0){
      u64 m[10];
#pragma unroll
      for (int i = 0; i < 10; ++i) m[i] = 0ull;
      for (int i = 0; i < 2560; ++i) t10_insert(m, sbuf[i]);
#pragma unroll
      for (int i = 0; i < 10; ++i) s_top[s][i] = m[i];
    }
    __syncthreads();
  }

  // extract points
  if (tid < 2){
    int np = 0;
    for (int i = 0; i < 10; ++i){
      u64 e = s_top[tid][i];
      if (e){
        uint32_t pix = 0xFFFFFFFFu - (uint32_t)(e & 0xFFFFFFFFull);
        s_pr[tid][np] = (int)(pix >> 8);
        s_pc[tid][np] = (int)(pix & 255u);
        ++np;
      }
    }
    s_np[tid] = np;
  }
  __syncthreads();

  // write dilated seed patches (<=180 px); duplicate writers compute identical values
  int* outb = out + (size_t)img * NPIX;
  const int nfg = s_np[0], nbg = s_np[1];
  const int npts = nfg + nbg;
  if (tid < npts*9){
    int k = tid / 9, d = tid - k*9;
    int pr = (k < nfg) ? s_pr[0][k] : s_pr[1][k - nfg];
    int pc = (k < nfg) ? s_pc[0][k] : s_pc[1][k - nfg];
    pr += d/3 - 1; pc += d%3 - 1;
    if (pr >= 0 && pr < 256 && pc >= 0 && pc < 256){
      bool fgd = false, bgd = false;
      for (int i = 0; i < nfg; ++i) fgd |= (abs(pr - s_pr[0][i]) <= 1) && (abs(pc - s_pc[0][i]) <= 1);
      for (int i = 0; i < nbg; ++i) bgd |= (abs(pr - s_pr[1][i]) <= 1) && (abs(pc - s_pc[1][i]) <= 1);
      int val = (fgd && bgd) ? IGN : (fgd ? 1 : 0);
      outb[pr*256 + pc] = val;
    }
  }
}

// ================= fused single-kernel fallback (proven round-3; needs no ws) ======
__global__ __launch_bounds__(1024, 4)
void apm_fused(const float* __restrict__ x, int* __restrict__ out){
  const int b = blockIdx.x;
  const int tid = threadIdx.x;
  const float* img = x + (size_t)b * NPIX;
  int* outb = out + (size_t)b * NPIX;

  __shared__ uint32_t hist[256];
  __shared__ float csum[256], cvsum[256];
  __shared__ u64 buf[2][256];
  __shared__ uint32_t s_kw[4];
  __shared__ int s_cnt[2];
  __shared__ int s_nroi, s_imin;
  __shared__ u64 s_best;
  __shared__ float s_lit;
  __shared__ int s_fail[2];
  __shared__ int s_pr[2][10], s_pc[2][10], s_np[2];

  if (tid < 256) hist[tid] = 0u;
  if (tid == 0){ s_cnt[0] = 0; s_cnt[1] = 0; s_nroi = 0; s_imin = 255; s_best = 0ull; }
  if (tid < 2){
    uint32_t o0, o1;
    tf2x32(0u, 1u, 0u, (uint32_t)(2*b + tid), o0, o1);
    s_kw[2*tid] = o0; s_kw[2*tid+1] = o1;
  }
  __syncthreads();

  uint32_t packed[16];
  {
    v4i f4 = {IGN, IGN, IGN, IGN};
    const float4* x4 = (const float4*)img;
    v4i* o4 = (v4i*)outb;
#pragma unroll
    for (int j = 0; j < 16; ++j){
      int p4 = tid + 1024*j;
      float4 v = x4[p4];
      o4[p4] = f4;
      uint32_t u0 = (uint32_t)min(max((int)floorf(v.x*255.0f),0),255);
      uint32_t u1 = (uint32_t)min(max((int)floorf(v.y*255.0f),0),255);
      uint32_t u2 = (uint32_t)min(max((int)floorf(v.z*255.0f),0),255);
      uint32_t u3 = (uint32_t)min(max((int)floorf(v.w*255.0f),0),255);
      packed[j] = u0 | (u1<<8) | (u2<<16) | (u3<<24);
      atomicAdd(&hist[u0],1u); atomicAdd(&hist[u1],1u);
      atomicAdd(&hist[u2],1u); atomicAdd(&hist[u3],1u);
    }
  }
  __syncthreads();
  if (tid < 256 && hist[tid]) atomicMin(&s_imin, tid);
  __syncthreads();
  const float img_min = (float)s_imin;
  if (tid < 256){
    float h = (float)hist[tid];
    csum[tid]  = h;
    cvsum[tid] = h * ((float)tid - img_min);
  }
  __syncthreads();
  for (int off = 1; off < 256; off <<= 1){
    float a = 0.f, c2 = 0.f;
    if (tid < 256 && tid >= off){ a = csum[tid-off]; c2 = cvsum[tid-off]; }
    __syncthreads();
    if (tid < 256 && tid >= off){ csum[tid] += a; cvsum[tid] += c2; }
    __syncthreads();
  }
  {
    float s_tot_o = cvsum[255] + img_min * csum[255];
    if (tid < 255){
      float w0 = csum[tid], w1 = 65536.0f - w0;
      float cs = cvsum[tid] + img_min * csum[tid];
      float m0 = cs / fmaxf(w0, 1e-12f);
      float m1 = (s_tot_o - cs) / fmaxf(w1, 1e-12f);
      float d = m0 - m1;
      float vb = (w0*w1) * (d*d);
      u64 pk = ((u64)__float_as_uint(vb) << 32) | (u64)(255 - tid);
      atomicMax(&s_best, pk);
    }
  }
  __syncthreads();
  if (tid == 0){
    int bestIdx = 255 - (int)(s_best & 0xFFFFFFFFull);
    float otsu = fminf(fmaxf((float)bestIdx, 1.0f), 254.0f);
    float n_tot = csum[255], s_tot = cvsum[255];
    float t_curr = otsu - img_min, t_prev = t_curr + 10.0f;
    int it = 0;
    while (fabsf(t_curr - t_prev) > 0.5f && it < 64){
      int idx = min(max((int)floorf(t_curr + img_min), 0), 255);
      float n_back = csum[idx], s_back = cvsum[idx];
      float n_fore = n_tot - n_back, s_fore = s_tot - s_back;
      float mean_back = (n_back > 0.0f) ? (s_back / fmaxf(n_back, 1.0f)) : 0.0f;
      float mean_fore = s_fore / fmaxf(n_fore, 1.0f);
      float t_next = (mean_back - mean_fore) /
                     (logf(fmaxf(mean_back, 1e-12f)) - logf(fmaxf(mean_fore, 1e-12f)));
      if (mean_back < 1e-12f) t_next = mean_fore * 0.5f;
      t_prev = t_curr; t_curr = t_next; ++it;
    }
    s_lit = t_curr + img_min;
  }
  __syncthreads();

  const float lit = s_lit;
  const uint32_t fk0 = s_kw[0], fk1 = s_kw[1], bk0 = s_kw[2], bk1 = s_kw[3];
  const uint32_t THRM = (0xFF000000u >> 9);
  int my_roi = 0;
#pragma unroll
  for (int j = 0; j < 16; ++j){
    uint32_t pk = packed[j];
    uint32_t pix0 = (uint32_t)(4*(tid + 1024*j));
#pragma unroll
    for (int s = 0; s < 4; ++s){
      uint32_t q = (pk >> (8*s)) & 255u;
      bool r = ((float)q > lit);
      my_roi += r ? 1 : 0;
      uint32_t o0, o1;
      tf2x32(r ? fk0 : bk0, r ? fk1 : bk1, 0u, pix0 + (uint32_t)s, o0, o1);
      uint32_t bits = o0 ^ o1;
      if ((bits >> 9) >= THRM){
        int r2 = r ? 0 : 1;
        int idx = atomicAdd(&s_cnt[r2], 1);
        if (idx < 256) buf[r2][idx] = packCand(bits, pix0 + (uint32_t)s);
      }
    }
  }
  for (int off = 32; off; off >>= 1) my_roi += __shfl_down(my_roi, off);
  if ((tid & 63) == 0) atomicAdd(&s_nroi, my_roi);
  __syncthreads();

  if (tid == 0){
    int m0r = s_nroi, m1r = NPIX - s_nroi;
    int c0 = s_cnt[0], c1 = s_cnt[1];
    s_fail[0] = (c0 > 256) || (c0 < 10 && c0 != m0r);
    s_fail[1] = (c1 > 256) || (c1 < 10 && c1 != m1r);
  }
  __syncthreads();

  if (s_fail[0] || s_fail[1]){
    __shared__ u64 smem[640];
    if (tid < 64){
      for (int r2 = 0; r2 < 2; ++r2){
        if (!s_fail[r2]) continue;
        uint32_t kk0 = s_kw[2*r2], kk1 = s_kw[2*r2+1];
        u64 t[10];
#pragma unroll
        for (int i = 0; i < 10; ++i) t[i] = 0ull;
        for (int k2 = 0; k2 < 1024; ++k2){
          uint32_t pix = (uint32_t)(tid + 64*k2);
          float v = img[pix];
          int q = min(max((int)floorf(v*255.0f),0),255);
          bool r = ((float)q > lit);
          if (r != (r2 == 0)) continue;
          uint32_t o0, o1; tf2x32(kk0, kk1, 0u, pix, o0, o1);
          t10_insert(t, packCand(o0 ^ o1, pix));
        }
#pragma unroll
        for (int i = 0; i < 10; ++i) smem[tid*10 + i] = t[i];
      }
    }
    __syncthreads();
    if (tid < 2 && s_fail[tid]){
      u64 t[10];
#pragma unroll
      for (int i = 0; i < 10; ++i) t[i] = 0ull;
      for (int i = 0; i < 640; ++i) t10_insert(t, smem[i]);
#pragma unroll
      for (int i = 0; i < 10; ++i) buf[tid][i] = t[i];
      s_cnt[tid] = 10;
    }
    __syncthreads();
  }

  if (tid == 0 || tid == 64){
    int r2 = (tid == 0) ? 0 : 1;
    int n = min(s_cnt[r2], 256);
    u64 t[10];
#pragma unroll
    for (int i = 0; i < 10; ++i) t[i] = 0ull;
    for (int i = 0; i < n; ++i) t10_insert(t, buf[r2][i]);
    int np = 0;
    for (int i = 0; i < 10; ++i){
      if (t[i]){
        uint32_t pix = 0xFFFFFFFFu - (uint32_t)(t[i] & 0xFFFFFFFFull);
        s_pr[r2][np] = (int)(pix >> 8);
        s_pc[r2][np] = (int)(pix & 255u);
        ++np;
      }
    }
    s_np[r2] = np;
  }
  __syncthreads();

  const int nfg = s_np[0], nbg = s_np[1];
  const int npts = nfg + nbg;
  if (tid < npts*9){
    int k = tid / 9, d = tid - k*9;
    int pr = (k < nfg) ? s_pr[0][k] : s_pr[1][k - nfg];
    int pc = (k < nfg) ? s_pc[0][k] : s_pc[1][k - nfg];
    pr += d/3 - 1; pc += d%3 - 1;
    if (pr >= 0 && pr < 256 && pc >= 0 && pc < 256){
      bool fgd = false, bgd = false;
      for (int i = 0; i < nfg; ++i) fgd |= (abs(pr - s_pr[0][i]) <= 1) && (abs(pc - s_pc[0][i]) <= 1);
      for (int i = 0; i < nbg; ++i) bgd |= (abs(pr - s_pr[1][i]) <= 1) && (abs(pc - s_pc[1][i]) <= 1);
      int val = (fgd && bgd) ? IGN : (fgd ? 1 : 0);
      outb[pr*256 + pc] = val;
    }
  }
}

extern "C" void kernel_launch(void* const* d_in, const int* in_sizes, int n_in,
                              void* d_out, int out_size, void* d_ws, size_t ws_size,
                              hipStream_t stream) {
  const float* x = (const float*)d_in[0];
  int* out = (int*)d_out;
  int B = in_sizes[0] / NPIX;

  // ws layout: [cand | phist | qcut | nroi | bcnt | u8cache]
  size_t cand_b  = (size_t)B * 8 * 2 * CAPB * 8;   // B*12288
  size_t phist_b = (size_t)B * 8 * 256 * 4;        // B*8192
  size_t qcut_b  = (size_t)B * 4;
  size_t nroi_b  = (size_t)B * 4;
  size_t bcnt_b  = (size_t)B * 8 * 2 * 4;          // B*64
  size_t base_need = cand_b + phist_b + qcut_b + nroi_b + bcnt_b;
  size_t u8_b = (size_t)B * 16384 * 4;             // B*65536

  if (ws_size < base_need){
    apm_fused<<<B, 1024, 0, stream>>>(x, out);
    return;
  }
  char* p = (char*)d_ws;
  u64*      cand  = (u64*)p;      p += cand_b;
  uint32_t* phist = (uint32_t*)p; p += phist_b;
  uint32_t* qcutp = (uint32_t*)p; p += qcut_b;
  uint32_t* nroip = (uint32_t*)p; p += nroi_b;
  uint32_t* bcnt  = (uint32_t*)p; p += bcnt_b;
  uint32_t* u8c   = (uint32_t*)p;
  int use_u8 = (ws_size >= base_need + u8_b) ? 1 : 0;

  k1_hist <<<B*8, 256, 0, stream>>>(x, out, phist, u8c, use_u8);
  k2_score<<<B*8, 256, 0, stream>>>(x, u8c, phist, qcutp, nroip, bcnt, cand, use_u8);
  k3_final<<<B,   256, 0, stream>>>(x, out, qcutp, nroip, bcnt, cand);
}

// Round 7
// 179.857 us; speedup vs baseline: 3.7132x; 1.1159x over previous
//
#include <hip/hip_runtime.h>
#include <stdint.h>

#define NPIX 65536
#define IGN (-255)
#define CAPB 96

typedef unsigned long long u64;
typedef int v4i __attribute__((ext_vector_type(4)));

// ---------------- threefry2x32 (exact JAX partitionable implementation) ----------------
__device__ __forceinline__ uint32_t rotl32(uint32_t v, uint32_t r){ return (v<<r)|(v>>(32u-r)); }

__device__ __forceinline__ void tf2x32(uint32_t k0, uint32_t k1, uint32_t x0, uint32_t x1,
                                       uint32_t &o0, uint32_t &o1){
  uint32_t k2 = k0 ^ k1 ^ 0x1BD11BDAu;
  x0 += k0; x1 += k1;
#define TFR(r) { x0 += x1; x1 = rotl32(x1,(r)); x1 ^= x0; }
  TFR(13u) TFR(15u) TFR(26u) TFR(6u)   x0 += k1; x1 += k2 + 1u;
  TFR(17u) TFR(29u) TFR(16u) TFR(24u)  x0 += k2; x1 += k0 + 2u;
  TFR(13u) TFR(15u) TFR(26u) TFR(6u)   x0 += k0; x1 += k1 + 3u;
  TFR(17u) TFR(29u) TFR(16u) TFR(24u)  x0 += k1; x1 += k2 + 4u;
  TFR(13u) TFR(15u) TFR(26u) TFR(6u)   x0 += k2; x1 += k0 + 5u;
#undef TFR
  o0 = x0; o1 = x1;
}

// specialized: x0 = 0, x1 = pix, k2 precomputed; returns o0 ^ o1 (partitionable bits)
__device__ __forceinline__ uint32_t tf_bits(uint32_t k0, uint32_t k1, uint32_t k2, uint32_t pix){
  uint32_t x0 = k0, x1 = pix + k1;
#define TFR(r) { x0 += x1; x1 = rotl32(x1,(r)); x1 ^= x0; }
  TFR(13u) TFR(15u) TFR(26u) TFR(6u)   x0 += k1; x1 += k2 + 1u;
  TFR(17u) TFR(29u) TFR(16u) TFR(24u)  x0 += k2; x1 += k0 + 2u;
  TFR(13u) TFR(15u) TFR(26u) TFR(6u)   x0 += k0; x1 += k1 + 3u;
  TFR(17u) TFR(29u) TFR(16u) TFR(24u)  x0 += k1; x1 += k2 + 4u;
  TFR(13u) TFR(15u) TFR(26u) TFR(6u)   x0 += k2; x1 += k0 + 5u;
#undef TFR
  return x0 ^ x1;
}

// pack score+index so that u64 max == (higher score, then lower index)
__device__ __forceinline__ u64 packCand(uint32_t bits, uint32_t pix){
  float f = __uint_as_float((bits >> 9) | 0x3f800000u) - 1.0f;  // jax uniform [0,1)
  uint32_t u = __float_as_uint(f) ^ 0x80000000u;                // monotone map (f>=0)
  return ((u64)u << 32) | (u64)(0xFFFFFFFFu - pix);
}

// sorted-descending 10-element list, sentinel 0
__device__ __forceinline__ void t10_insert(u64* l, u64 c){
  if (c > l[9]) {
    l[9] = c;
#pragma unroll
    for (int i = 9; i > 0; --i){
      u64 a = l[i-1], b2 = l[i];
      if (b2 > a){ l[i-1] = b2; l[i] = a; }
    }
  }
}

// ================= K1: histogram + u8 cache (no out fill) =================
__global__ __launch_bounds__(256)
void k1_hist(const float* __restrict__ x, uint32_t* __restrict__ phist,
             uint32_t* __restrict__ u8c){
  const int img = blockIdx.x >> 3;
  const int chk = blockIdx.x & 7;
  const int tid = threadIdx.x;
  const float4* x4 = (const float4*)(x + (size_t)img * NPIX);

  __shared__ uint32_t h4[1024];   // [bin*4 + sub]
  h4[tid] = 0u; h4[tid+256] = 0u; h4[tid+512] = 0u; h4[tid+768] = 0u;
  __syncthreads();

  const int sub = tid & 3;
#pragma unroll
  for (int j = 0; j < 8; ++j){
    int p4 = chk*2048 + j*256 + tid;
    float4 v = x4[p4];
    uint32_t q0 = (uint32_t)min(max((int)floorf(v.x*255.0f),0),255);
    uint32_t q1 = (uint32_t)min(max((int)floorf(v.y*255.0f),0),255);
    uint32_t q2 = (uint32_t)min(max((int)floorf(v.z*255.0f),0),255);
    uint32_t q3 = (uint32_t)min(max((int)floorf(v.w*255.0f),0),255);
    u8c[(size_t)img*16384 + p4] = q0 | (q1<<8) | (q2<<16) | (q3<<24);
    atomicAdd(&h4[q0*4+sub],1u); atomicAdd(&h4[q1*4+sub],1u);
    atomicAdd(&h4[q2*4+sub],1u); atomicAdd(&h4[q3*4+sub],1u);
  }
  __syncthreads();
  // plain store of this block's partial histogram (no global atomics, no pre-zero)
  phist[(size_t)(img*8+chk)*256 + tid] = h4[tid*4] + h4[tid*4+1] + h4[tid*4+2] + h4[tid*4+3];
}

// ================= K1b: thresholds once per image =================
__global__ __launch_bounds__(256)
void k1b_thresh(const uint32_t* __restrict__ phist, uint32_t* __restrict__ qcutp,
                uint32_t* __restrict__ nroip){
  const int img = blockIdx.x;
  const int tid = threadIdx.x;

  __shared__ float csum[256], cvsum[256];
  __shared__ u64 s_best;
  __shared__ int s_imin;

  if (tid == 0){ s_imin = 255; s_best = 0ull; }
  uint32_t h = 0;
#pragma unroll
  for (int k = 0; k < 8; ++k) h += phist[(size_t)(img*8+k)*256 + tid];
  __syncthreads();
  if (h) atomicMin(&s_imin, tid);
  __syncthreads();
  const float img_min = (float)s_imin;
  csum[tid]  = (float)h;
  cvsum[tid] = (float)h * ((float)tid - img_min);
  __syncthreads();
  // Hillis-Steele scan: all partial sums are exact ints < 2^24 -> bit-exact vs cumsum
  for (int off = 1; off < 256; off <<= 1){
    float a = 0.f, c2 = 0.f;
    if (tid >= off){ a = csum[tid-off]; c2 = cvsum[tid-off]; }
    __syncthreads();
    if (tid >= off){ csum[tid] += a; cvsum[tid] += c2; }
    __syncthreads();
  }
  // Otsu argmax (first max wins)
  {
    float s_tot_o = cvsum[255] + img_min * csum[255];
    if (tid < 255){
      float w0 = csum[tid], w1 = 65536.0f - w0;
      float cs = cvsum[tid] + img_min * csum[tid];
      float m0 = cs / fmaxf(w0, 1e-12f);
      float m1 = (s_tot_o - cs) / fmaxf(w1, 1e-12f);
      float d = m0 - m1;
      float vb = (w0*w1) * (d*d);
      u64 pk = ((u64)__float_as_uint(vb) << 32) | (u64)(255 - tid);
      atomicMax(&s_best, pk);
    }
  }
  __syncthreads();
  if (tid == 0){
    int bestIdx = 255 - (int)(s_best & 0xFFFFFFFFull);
    float otsu = fminf(fmaxf((float)bestIdx, 1.0f), 254.0f);
    float n_tot = csum[255], s_tot = cvsum[255];
    float t_curr = otsu - img_min, t_prev = t_curr + 10.0f;
    int it = 0;
    while (fabsf(t_curr - t_prev) > 0.5f && it < 64){
      int idx = min(max((int)floorf(t_curr + img_min), 0), 255);
      float n_back = csum[idx], s_back = cvsum[idx];
      float n_fore = n_tot - n_back, s_fore = s_tot - s_back;
      float mean_back = (n_back > 0.0f) ? (s_back / fmaxf(n_back, 1.0f)) : 0.0f;
      float mean_fore = s_fore / fmaxf(n_fore, 1.0f);
      float t_next = (mean_back - mean_fore) /
                     (logf(fmaxf(mean_back, 1e-12f)) - logf(fmaxf(mean_fore, 1e-12f)));
      if (mean_back < 1e-12f) t_next = mean_fore * 0.5f;
      t_prev = t_curr; t_curr = t_next; ++it;
    }
    float lit = t_curr + img_min;
    int qcut = (int)floorf(lit) + 1;     // roi: q > lit  <=>  q >= qcut (q integer)
    uint32_t nroi;
    if (qcut <= 0)        nroi = NPIX;
    else if (qcut > 255)  nroi = 0u;
    else                  nroi = NPIX - (uint32_t)csum[qcut-1];
    qcutp[img] = (uint32_t)qcut;
    nroip[img] = nroi;
  }
}

// ================= K2: IGN fill + scoring =================
__global__ __launch_bounds__(256)
void k2_score(const uint32_t* __restrict__ u8c, int* __restrict__ out,
              const uint32_t* __restrict__ qcutp, uint32_t* __restrict__ bcnt,
              u64* __restrict__ cand){
  const int img = blockIdx.x >> 3;
  const int chk = blockIdx.x & 7;
  const int tid = threadIdx.x;

  __shared__ uint32_t s_kw[4], s_cnt[2];
  __shared__ u64 s_cand[2][CAPB];

  if (tid < 2){
    uint32_t o0, o1;
    tf2x32(0u, 1u, 0u, (uint32_t)(2*img + tid), o0, o1);
    s_kw[2*tid] = o0; s_kw[2*tid+1] = o1;
  }
  if (tid == 0){ s_cnt[0] = 0u; s_cnt[1] = 0u; }
  const int qcut = (int)qcutp[img];
  __syncthreads();

  // ---- fill output chunk with IGNORE (coalesced NT int4) ----
  {
    v4i* o4 = (v4i*)(out + (size_t)img * NPIX);
    const v4i f4 = {IGN, IGN, IGN, IGN};
#pragma unroll
    for (int j = 0; j < 8; ++j)
      __builtin_nontemporal_store(f4, &o4[chk*2048 + j*256 + tid]);
  }

  // ---- scoring: 16 px per uint4 load, 16 unrolled threefry chains ----
  const uint32_t fk0 = s_kw[0], fk1 = s_kw[1], bk0 = s_kw[2], bk1 = s_kw[3];
  const uint32_t fk2 = fk0 ^ fk1 ^ 0x1BD11BDAu;
  const uint32_t bk2 = bk0 ^ bk1 ^ 0x1BD11BDAu;
  const uint4* u4 = (const uint4*)(u8c + (size_t)img*16384);
#pragma unroll
  for (int j = 0; j < 2; ++j){
    int wi = chk*512 + j*256 + tid;      // uint4 index within image
    uint4 w4 = u4[wi];
    uint32_t pix0 = (uint32_t)(wi*16);
    uint32_t ws4[4] = {w4.x, w4.y, w4.z, w4.w};
#pragma unroll
    for (int wsub = 0; wsub < 4; ++wsub){
      uint32_t w = ws4[wsub];
#pragma unroll
      for (int s = 0; s < 4; ++s){
        int q = (int)((w >> (8*s)) & 255u);
        bool r = (q >= qcut);
        uint32_t pix = pix0 + (uint32_t)(wsub*4 + s);
        uint32_t bits = tf_bits(r?fk0:bk0, r?fk1:bk1, r?fk2:bk2, pix);
        // mantissa-aligned cut (top 1/256 of score space; no tie straddles it)
        if (bits >= 0xFF000000u){
          int r2 = r ? 0 : 1;
          uint32_t idx = atomicAdd(&s_cnt[r2], 1u);
          if (idx < CAPB) s_cand[r2][idx] = packCand(bits, pix);
        }
      }
    }
  }
  __syncthreads();
  if (tid < 2) bcnt[(size_t)(img*8+chk)*2 + tid] = s_cnt[tid];   // raw (uncapped)
  {
    int s = tid >> 7, idx = tid & 127;
    int n = min((int)s_cnt[s], CAPB);
    if (idx < n) cand[((size_t)(img*8+chk)*2 + s)*CAPB + idx] = s_cand[s][idx];
  }
}

// ================= K3: gather candidates, top-10, write seeds =================
__global__ __launch_bounds__(256)
void k3_final(const float* __restrict__ x, int* __restrict__ out,
              const uint32_t* __restrict__ qcutp, const uint32_t* __restrict__ nroip,
              const uint32_t* __restrict__ bcnt, const u64* __restrict__ cand){
  const int img = blockIdx.x;
  const int tid = threadIdx.x;

  __shared__ u64 sbuf[2560];
  __shared__ u64 s_top[2][10];
  __shared__ int s_off[2][9], s_fail[2];
  __shared__ uint32_t s_kw[4];
  __shared__ int s_pr[2][10], s_pc[2][10], s_np[2];

  if (tid < 2){
    uint32_t o0, o1;
    tf2x32(0u, 1u, 0u, (uint32_t)(2*img + tid), o0, o1);
    s_kw[2*tid] = o0; s_kw[2*tid+1] = o1;
  }
  if (tid == 0){
    uint32_t nroi = nroip[img];
    for (int s = 0; s < 2; ++s){
      int off = 0, fail = 0;
      for (int k = 0; k < 8; ++k){
        uint32_t raw = bcnt[(size_t)(img*8+k)*2 + s];
        if (raw > (uint32_t)CAPB) fail = 1;
        int ck = (int)min(raw, (uint32_t)CAPB);
        s_off[s][k] = off; off += ck;
      }
      s_off[s][8] = off;
      int region = s ? (int)(NPIX - nroi) : (int)nroi;
      if (off < 10 && off != region) fail = 1;
      s_fail[s] = fail;
    }
  }
  __syncthreads();

  // compact candidates into LDS: threads [0,128) stream0, [128,256) stream1
  {
    int s = tid >> 7, idx = tid & 127;
#pragma unroll
    for (int k = 0; k < 8; ++k){
      int ck = s_off[s][k+1] - s_off[s][k];
      if (idx < ck) sbuf[s*1280 + s_off[s][k] + idx] = cand[((size_t)(img*8+k)*2 + s)*CAPB + idx];
    }
  }
  __syncthreads();
  if (tid == 0 || tid == 128){
    int s = tid >> 7;
    if (!s_fail[s]){
      u64 t[10];
#pragma unroll
      for (int i = 0; i < 10; ++i) t[i] = 0ull;
      int n = s_off[s][8];
      for (int i = 0; i < n; ++i) t10_insert(t, sbuf[s*1280 + i]);
#pragma unroll
      for (int i = 0; i < 10; ++i) s_top[s][i] = t[i];
    }
  }
  __syncthreads();

  // fallback rescan (statistically never runs; guarantees correctness)
  const int qcut = (int)qcutp[img];
  for (int s = 0; s < 2; ++s){
    if (!s_fail[s]) continue;          // uniform branch (shared)
    uint32_t kk0 = s_kw[2*s], kk1 = s_kw[2*s+1], kk2 = kk0 ^ kk1 ^ 0x1BD11BDAu;
    u64 t[10];
#pragma unroll
    for (int i = 0; i < 10; ++i) t[i] = 0ull;
    for (int k = 0; k < 256; ++k){
      uint32_t pix = (uint32_t)(tid + 256*k);
      float v = x[(size_t)img*NPIX + pix];
      int q = min(max((int)floorf(v*255.0f),0),255);
      bool r = (q >= qcut);
      if (r == (s == 0)) t10_insert(t, packCand(tf_bits(kk0, kk1, kk2, pix), pix));
    }
#pragma unroll
    for (int i = 0; i < 10; ++i) sbuf[tid*10 + i] = t[i];
    __syncthreads();
    if (tid == 0){
      u64 m[10];
#pragma unroll
      for (int i = 0; i < 10; ++i) m[i] = 0ull;
      for (int i = 0; i < 2560; ++i) t10_insert(m, sbuf[i]);
#pragma unroll
      for (int i = 0; i < 10; ++i) s_top[s][i] = m[i];
    }
    __syncthreads();
  }

  // extract points
  if (tid < 2){
    int np = 0;
    for (int i = 0; i < 10; ++i){
      u64 e = s_top[tid][i];
      if (e){
        uint32_t pix = 0xFFFFFFFFu - (uint32_t)(e & 0xFFFFFFFFull);
        s_pr[tid][np] = (int)(pix >> 8);
        s_pc[tid][np] = (int)(pix & 255u);
        ++np;
      }
    }
    s_np[tid] = np;
  }
  __syncthreads();

  // write dilated seed patches (<=180 px); duplicate writers compute identical values
  int* outb = out + (size_t)img * NPIX;
  const int nfg = s_np[0], nbg = s_np[1];
  const int npts = nfg + nbg;
  if (tid < npts*9){
    int k = tid / 9, d = tid - k*9;
    int pr = (k < nfg) ? s_pr[0][k] : s_pr[1][k - nfg];
    int pc = (k < nfg) ? s_pc[0][k] : s_pc[1][k - nfg];
    pr += d/3 - 1; pc += d%3 - 1;
    if (pr >= 0 && pr < 256 && pc >= 0 && pc < 256){
      bool fgd = false, bgd = false;
      for (int i = 0; i < nfg; ++i) fgd |= (abs(pr - s_pr[0][i]) <= 1) && (abs(pc - s_pc[0][i]) <= 1);
      for (int i = 0; i < nbg; ++i) bgd |= (abs(pr - s_pr[1][i]) <= 1) && (abs(pc - s_pc[1][i]) <= 1);
      int val = (fgd && bgd) ? IGN : (fgd ? 1 : 0);
      outb[pr*256 + pc] = val;
    }
  }
}

// ================= fused single-kernel fallback (proven round-3; needs no ws) ======
__global__ __launch_bounds__(1024, 4)
void apm_fused(const float* __restrict__ x, int* __restrict__ out){
  const int b = blockIdx.x;
  const int tid = threadIdx.x;
  const float* img = x + (size_t)b * NPIX;
  int* outb = out + (size_t)b * NPIX;

  __shared__ uint32_t hist[256];
  __shared__ float csum[256], cvsum[256];
  __shared__ u64 buf[2][256];
  __shared__ uint32_t s_kw[4];
  __shared__ int s_cnt[2];
  __shared__ int s_nroi, s_imin;
  __shared__ u64 s_best;
  __shared__ float s_lit;
  __shared__ int s_fail[2];
  __shared__ int s_pr[2][10], s_pc[2][10], s_np[2];

  if (tid < 256) hist[tid] = 0u;
  if (tid == 0){ s_cnt[0] = 0; s_cnt[1] = 0; s_nroi = 0; s_imin = 255; s_best = 0ull; }
  if (tid < 2){
    uint32_t o0, o1;
    tf2x32(0u, 1u, 0u, (uint32_t)(2*b + tid), o0, o1);
    s_kw[2*tid] = o0; s_kw[2*tid+1] = o1;
  }
  __syncthreads();

  uint32_t packed[16];
  {
    v4i f4 = {IGN, IGN, IGN, IGN};
    const float4* x4 = (const float4*)img;
    v4i* o4 = (v4i*)outb;
#pragma unroll
    for (int j = 0; j < 16; ++j){
      int p4 = tid + 1024*j;
      float4 v = x4[p4];
      o4[p4] = f4;
      uint32_t u0 = (uint32_t)min(max((int)floorf(v.x*255.0f),0),255);
      uint32_t u1 = (uint32_t)min(max((int)floorf(v.y*255.0f),0),255);
      uint32_t u2 = (uint32_t)min(max((int)floorf(v.z*255.0f),0),255);
      uint32_t u3 = (uint32_t)min(max((int)floorf(v.w*255.0f),0),255);
      packed[j] = u0 | (u1<<8) | (u2<<16) | (u3<<24);
      atomicAdd(&hist[u0],1u); atomicAdd(&hist[u1],1u);
      atomicAdd(&hist[u2],1u); atomicAdd(&hist[u3],1u);
    }
  }
  __syncthreads();
  if (tid < 256 && hist[tid]) atomicMin(&s_imin, tid);
  __syncthreads();
  const float img_min = (float)s_imin;
  if (tid < 256){
    float h = (float)hist[tid];
    csum[tid]  = h;
    cvsum[tid] = h * ((float)tid - img_min);
  }
  __syncthreads();
  for (int off = 1; off < 256; off <<= 1){
    float a = 0.f, c2 = 0.f;
    if (tid < 256 && tid >= off){ a = csum[tid-off]; c2 = cvsum[tid-off]; }
    __syncthreads();
    if (tid < 256 && tid >= off){ csum[tid] += a; cvsum[tid] += c2; }
    __syncthreads();
  }
  {
    float s_tot_o = cvsum[255] + img_min * csum[255];
    if (tid < 255){
      float w0 = csum[tid], w1 = 65536.0f - w0;
      float cs = cvsum[tid] + img_min * csum[tid];
      float m0 = cs / fmaxf(w0, 1e-12f);
      float m1 = (s_tot_o - cs) / fmaxf(w1, 1e-12f);
      float d = m0 - m1;
      float vb = (w0*w1) * (d*d);
      u64 pk = ((u64)__float_as_uint(vb) << 32) | (u64)(255 - tid);
      atomicMax(&s_best, pk);
    }
  }
  __syncthreads();
  if (tid == 0){
    int bestIdx = 255 - (int)(s_best & 0xFFFFFFFFull);
    float otsu = fminf(fmaxf((float)bestIdx, 1.0f), 254.0f);
    float n_tot = csum[255], s_tot = cvsum[255];
    float t_curr = otsu - img_min, t_prev = t_curr + 10.0f;
    int it = 0;
    while (fabsf(t_curr - t_prev) > 0.5f && it < 64){
      int idx = min(max((int)floorf(t_curr + img_min), 0), 255);
      float n_back = csum[idx], s_back = cvsum[idx];
      float n_fore = n_tot - n_back, s_fore = s_tot - s_back;
      float mean_back = (n_back > 0.0f) ? (s_back / fmaxf(n_back, 1.0f)) : 0.0f;
      float mean_fore = s_fore / fmaxf(n_fore, 1.0f);
      float t_next = (mean_back - mean_fore) /
                     (logf(fmaxf(mean_back, 1e-12f)) - logf(fmaxf(mean_fore, 1e-12f)));
      if (mean_back < 1e-12f) t_next = mean_fore * 0.5f;
      t_prev = t_curr; t_curr = t_next; ++it;
    }
    s_lit = t_curr + img_min;
  }
  __syncthreads();

  const float lit = s_lit;
  const uint32_t fk0 = s_kw[0], fk1 = s_kw[1], bk0 = s_kw[2], bk1 = s_kw[3];
  const uint32_t THRM = (0xFF000000u >> 9);
  int my_roi = 0;
#pragma unroll
  for (int j = 0; j < 16; ++j){
    uint32_t pk = packed[j];
    uint32_t pix0 = (uint32_t)(4*(tid + 1024*j));
#pragma unroll
    for (int s = 0; s < 4; ++s){
      uint32_t q = (pk >> (8*s)) & 255u;
      bool r = ((float)q > lit);
      my_roi += r ? 1 : 0;
      uint32_t o0, o1;
      tf2x32(r ? fk0 : bk0, r ? fk1 : bk1, 0u, pix0 + (uint32_t)s, o0, o1);
      uint32_t bits = o0 ^ o1;
      if ((bits >> 9) >= THRM){
        int r2 = r ? 0 : 1;
        int idx = atomicAdd(&s_cnt[r2], 1);
        if (idx < 256) buf[r2][idx] = packCand(bits, pix0 + (uint32_t)s);
      }
    }
  }
  for (int off = 32; off; off >>= 1) my_roi += __shfl_down(my_roi, off);
  if ((tid & 63) == 0) atomicAdd(&s_nroi, my_roi);
  __syncthreads();

  if (tid == 0){
    int m0r = s_nroi, m1r = NPIX - s_nroi;
    int c0 = s_cnt[0], c1 = s_cnt[1];
    s_fail[0] = (c0 > 256) || (c0 < 10 && c0 != m0r);
    s_fail[1] = (c1 > 256) || (c1 < 10 && c1 != m1r);
  }
  __syncthreads();

  if (s_fail[0] || s_fail[1]){
    __shared__ u64 smem[640];
    if (tid < 64){
      for (int r2 = 0; r2 < 2; ++r2){
        if (!s_fail[r2]) continue;
        uint32_t kk0 = s_kw[2*r2], kk1 = s_kw[2*r2+1];
        u64 t[10];
#pragma unroll
        for (int i = 0; i < 10; ++i) t[i] = 0ull;
        for (int k2 = 0; k2 < 1024; ++k2){
          uint32_t pix = (uint32_t)(tid + 64*k2);
          float v = img[pix];
          int q = min(max((int)floorf(v*255.0f),0),255);
          bool r = ((float)q > lit);
          if (r != (r2 == 0)) continue;
          uint32_t o0, o1; tf2x32(kk0, kk1, 0u, pix, o0, o1);
          t10_insert(t, packCand(o0 ^ o1, pix));
        }
#pragma unroll
        for (int i = 0; i < 10; ++i) smem[tid*10 + i] = t[i];
      }
    }
    __syncthreads();
    if (tid < 2 && s_fail[tid]){
      u64 t[10];
#pragma unroll
      for (int i = 0; i < 10; ++i) t[i] = 0ull;
      for (int i = 0; i < 640; ++i) t10_insert(t, smem[i]);
#pragma unroll
      for (int i = 0; i < 10; ++i) buf[tid][i] = t[i];
      s_cnt[tid] = 10;
    }
    __syncthreads();
  }

  if (tid == 0 || tid == 64){
    int r2 = (tid == 0) ? 0 : 1;
    int n = min(s_cnt[r2], 256);
    u64 t[10];
#pragma unroll
    for (int i = 0; i < 10; ++i) t[i] = 0ull;
    for (int i = 0; i < n; ++i) t10_insert(t, buf[r2][i]);
    int np = 0;
    for (int i = 0; i < 10; ++i){
      if (t[i]){
        uint32_t pix = 0xFFFFFFFFu - (uint32_t)(t[i] & 0xFFFFFFFFull);
        s_pr[r2][np] = (int)(pix >> 8);
        s_pc[r2][np] = (int)(pix & 255u);
        ++np;
      }
    }
    s_np[r2] = np;
  }
  __syncthreads();

  const int nfg = s_np[0], nbg = s_np[1];
  const int npts = nfg + nbg;
  if (tid < npts*9){
    int k = tid / 9, d = tid - k*9;
    int pr = (k < nfg) ? s_pr[0][k] : s_pr[1][k - nfg];
    int pc = (k < nfg) ? s_pc[0][k] : s_pc[1][k - nfg];
    pr += d/3 - 1; pc += d%3 - 1;
    if (pr >= 0 && pr < 256 && pc >= 0 && pc < 256){
      bool fgd = false, bgd = false;
      for (int i = 0; i < nfg; ++i) fgd |= (abs(pr - s_pr[0][i]) <= 1) && (abs(pc - s_pc[0][i]) <= 1);
      for (int i = 0; i < nbg; ++i) bgd |= (abs(pr - s_pr[1][i]) <= 1) && (abs(pc - s_pc[1][i]) <= 1);
      int val = (fgd && bgd) ? IGN : (fgd ? 1 : 0);
      outb[pr*256 + pc] = val;
    }
  }
}

extern "C" void kernel_launch(void* const* d_in, const int* in_sizes, int n_in,
                              void* d_out, int out_size, void* d_ws, size_t ws_size,
                              hipStream_t stream) {
  const float* x = (const float*)d_in[0];
  int* out = (int*)d_out;
  int B = in_sizes[0] / NPIX;

  // ws layout: [cand | phist | qcut | nroi | bcnt | u8cache]
  size_t cand_b  = (size_t)B * 8 * 2 * CAPB * 8;   // B*12288
  size_t phist_b = (size_t)B * 8 * 256 * 4;        // B*8192
  size_t qcut_b  = (size_t)B * 4;
  size_t nroi_b  = (size_t)B * 4;
  size_t bcnt_b  = (size_t)B * 8 * 2 * 4;          // B*64
  size_t u8_b    = (size_t)B * 16384 * 4;          // B*65536
  size_t need = cand_b + phist_b + qcut_b + nroi_b + bcnt_b + u8_b;

  if (ws_size < need){
    apm_fused<<<B, 1024, 0, stream>>>(x, out);
    return;
  }
  char* p = (char*)d_ws;
  u64*      cand  = (u64*)p;      p += cand_b;
  uint32_t* phist = (uint32_t*)p; p += phist_b;
  uint32_t* qcutp = (uint32_t*)p; p += qcut_b;
  uint32_t* nroip = (uint32_t*)p; p += nroi_b;
  uint32_t* bcnt  = (uint32_t*)p; p += bcnt_b;
  uint32_t* u8c   = (uint32_t*)p;

  k1_hist   <<<B*8, 256, 0, stream>>>(x, phist, u8c);
  k1b_thresh<<<B,   256, 0, stream>>>(phist, qcutp, nroip);
  k2_score  <<<B*8, 256, 0, stream>>>(u8c, out, qcutp, bcnt, cand);
  k3_final  <<<B,   256, 0, stream>>>(x, out, qcutp, nroip, bcnt, cand);
}